// Round 6
// baseline (131.817 us; speedup 1.0000x reference)
//
#include <hip/hip_runtime.h>

namespace {
constexpr int L_ = 512;
constexpr int B_ = 1024;
constexpr int K_ = 64;
constexpr int START_I = 62;
constexpr int STOP_I = 63;
}

__device__ __forceinline__ float bcast0(float x) {
    return __int_as_float(__builtin_amdgcn_readfirstlane(__float_as_int(x)));
}

#define RL(j) __int_as_float(__builtin_amdgcn_readlane(pi, (j)))

// Read 8 broadcast values into bank Qv (SGPRs via v_readlane).
#define G_READ(Qv, base)                                                    \
    Qv##0 = RL((base) + 0); Qv##1 = RL((base) + 1);                         \
    Qv##2 = RL((base) + 2); Qv##3 = RL((base) + 3);                         \
    Qv##4 = RL((base) + 4); Qv##5 = RL((base) + 5);                         \
    Qv##6 = RL((base) + 6); Qv##7 = RL((base) + 7);

// Consume bank Qv (issued one group earlier -> >=8 insts of hazard distance).
#define G_FMA(Qv, Ea, Eb, Ec, Ed, Ee, Ef, Eg, Eh)                           \
    a0 = fmaf(Qv##0, Ea, a0); a1 = fmaf(Qv##1, Eb, a1);                     \
    a2 = fmaf(Qv##2, Ec, a2); a3 = fmaf(Qv##3, Ed, a3);                     \
    a4 = fmaf(Qv##4, Ee, a4); a5 = fmaf(Qv##5, Ef, a5);                     \
    a6 = fmaf(Qv##6, Eg, a6); a7 = fmaf(Qv##7, Eh, a7);

// One forward-recursion step in the LINEAR domain.
// p'_i = (sum_j E[i][j] p_j) * exp(emit_i). EREG = emit loaded 8 steps ago.
// RECEN: rescale by an exact power of two from lane 0's exponent (proven R2).
#define CRF_STEP(EREG, TNEXT, RECEN)                                        \
    do {                                                                    \
        float ee = exp2f(EREG * 1.4426950408889634f);                       \
        {                                                                   \
            int tp = (TNEXT) < len ? (TNEXT) : (len - 1);                   \
            EREG = eb[(long)tp * (B_ * K_)];                                \
        }                                                                   \
        int pi = __float_as_int(p);                                         \
        float a0 = 0.f, a1 = 0.f, a2 = 0.f, a3 = 0.f;                       \
        float a4 = 0.f, a5 = 0.f, a6 = 0.f, a7 = 0.f;                       \
        float qa0, qa1, qa2, qa3, qa4, qa5, qa6, qa7;                       \
        float qb0, qb1, qb2, qb3, qb4, qb5, qb6, qb7;                       \
        G_READ(qa, 0)                                                       \
        G_READ(qb, 8)   G_FMA(qa, E0,  E1,  E2,  E3,  E4,  E5,  E6,  E7)    \
        G_READ(qa, 16)  G_FMA(qb, E8,  E9,  E10, E11, E12, E13, E14, E15)   \
        G_READ(qb, 24)  G_FMA(qa, E16, E17, E18, E19, E20, E21, E22, E23)   \
        G_READ(qa, 32)  G_FMA(qb, E24, E25, E26, E27, E28, E29, E30, E31)   \
        G_READ(qb, 40)  G_FMA(qa, E32, E33, E34, E35, E36, E37, E38, E39)   \
        G_READ(qa, 48)  G_FMA(qb, E40, E41, E42, E43, E44, E45, E46, E47)   \
        G_READ(qb, 56)  G_FMA(qa, E48, E49, E50, E51, E52, E53, E54, E55)   \
                        G_FMA(qb, E56, E57, E58, E59, E60, E61, E62, E63)   \
        float pn = (((a0 + a1) + (a2 + a3)) + ((a4 + a5) + (a6 + a7))) * ee;\
        if (RECEN) {                                                        \
            float p0 = bcast0(pn);                                          \
            int kk = (int)(__float_as_uint(p0) >> 23) - 127;                \
            pn *= __uint_as_float((unsigned)(127 - kk) << 23);              \
            base2 += (float)kk;                                             \
        }                                                                   \
        p = pn;                                                             \
    } while (0)

__global__ __launch_bounds__(64)
__attribute__((amdgpu_waves_per_eu(1, 1)))
void crf_kernel(
    const float* __restrict__ emit,    // (L,B,K)
    const float* __restrict__ trans,   // (K,K)
    const int* __restrict__ labels,    // (L,B)
    const float* __restrict__ masks,   // (L,B)
    float* __restrict__ out)           // (B,)
{
    const int lane = threadIdx.x & 63;
    const int b = blockIdx.x;
    constexpr float LOG2E = 1.4426950408889634f;
    constexpr float LN2 = 0.6931471805599453f;

    // E row `lane` of exp(T) in 64 named scalars (VGPR-resident, proven R5:
    // VGPR_Count 132, asm-laundered against remat).
    const float4* t4 = reinterpret_cast<const float4*>(trans + lane * K_);
#define MKE(q, A, Bn, C, D)                                                 \
    float4 tv##q = t4[q];                                                   \
    float A  = exp2f(tv##q.x * LOG2E);                                      \
    float Bn = exp2f(tv##q.y * LOG2E);                                      \
    float C  = exp2f(tv##q.z * LOG2E);                                      \
    float D  = exp2f(tv##q.w * LOG2E);                                      \
    asm("" : "+v"(A), "+v"(Bn), "+v"(C), "+v"(D));
    MKE(0,  E0,  E1,  E2,  E3)   MKE(1,  E4,  E5,  E6,  E7)
    MKE(2,  E8,  E9,  E10, E11)  MKE(3,  E12, E13, E14, E15)
    MKE(4,  E16, E17, E18, E19)  MKE(5,  E20, E21, E22, E23)
    MKE(6,  E24, E25, E26, E27)  MKE(7,  E28, E29, E30, E31)
    MKE(8,  E32, E33, E34, E35)  MKE(9,  E36, E37, E38, E39)
    MKE(10, E40, E41, E42, E43)  MKE(11, E44, E45, E46, E47)
    MKE(12, E48, E49, E50, E51)  MKE(13, E52, E53, E54, E55)
    MKE(14, E56, E57, E58, E59)  MKE(15, E60, E61, E62, E63)
#undef MKE

    // len[b] = sum_t masks[t,b]  (masks are prefix masks)
    int len = 0;
    #pragma unroll
    for (int c = 0; c < L_ / 64; ++c)
        len += (int)masks[(c * 64 + lane) * B_ + b];
    #pragma unroll
    for (int off = 32; off >= 1; off >>= 1)
        len += __shfl_xor(len, off);

    // Linear-domain state: score_i = (log2 p_i + base2)*ln2.
    float p = (lane == START_I) ? 1.0f : 0.0f;
    float base2 = 0.0f;
    const float* eb = emit + b * K_ + lane;

    // 8-deep emit prefetch ring (len >= 128 always).
    float e0 = eb[0L * (B_ * K_)];
    float e1 = eb[1L * (B_ * K_)];
    float e2 = eb[2L * (B_ * K_)];
    float e3 = eb[3L * (B_ * K_)];
    float e4 = eb[4L * (B_ * K_)];
    float e5 = eb[5L * (B_ * K_)];
    float e6 = eb[6L * (B_ * K_)];
    float e7 = eb[7L * (B_ * K_)];

    int t = 0;
    for (; t + 8 <= len; t += 8) {
        CRF_STEP(e0, t + 8, 0);
        CRF_STEP(e1, t + 9, 0);
        CRF_STEP(e2, t + 10, 0);
        CRF_STEP(e3, t + 11, 1);
        CRF_STEP(e4, t + 12, 0);
        CRF_STEP(e5, t + 13, 0);
        CRF_STEP(e6, t + 14, 0);
        CRF_STEP(e7, t + 15, 1);
    }
    if (t < len) { CRF_STEP(e0, len - 1, 1); ++t; }
    if (t < len) { CRF_STEP(e1, len - 1, 1); ++t; }
    if (t < len) { CRF_STEP(e2, len - 1, 1); ++t; }
    if (t < len) { CRF_STEP(e3, len - 1, 1); ++t; }
    if (t < len) { CRF_STEP(e4, len - 1, 1); ++t; }
    if (t < len) { CRF_STEP(e5, len - 1, 1); ++t; }
    if (t < len) { CRF_STEP(e6, len - 1, 1); ++t; }

    // partition = LSE_k(score_k + T[STOP,k])
    float v = fmaf(__log2f(p) + base2, LN2, trans[STOP_I * K_ + lane]);
    float M = v;
    #pragma unroll
    for (int off = 32; off >= 1; off >>= 1)
        M = fmaxf(M, __shfl_xor(M, off));
    float pe = exp2f((v - M) * LOG2E);
    #pragma unroll
    for (int off = 32; off >= 1; off >>= 1)
        pe += __shfl_xor(pe, off);
    float part = fmaf(__log2f(pe), LN2, M);

    // gold score: lanes cover t = c*64 + lane
    float g = 0.0f;
    #pragma unroll
    for (int c = 0; c < L_ / 64; ++c) {
        int tt = c * 64 + lane;
        if (tt < len) {
            int lt = labels[tt * B_ + b];
            int lp;
            if (tt == 0) lp = START_I;
            else lp = labels[(tt - 1) * B_ + b];
            g += trans[lt * K_ + lp] + emit[((long)tt * B_ + b) * K_ + lt];
        }
    }
    #pragma unroll
    for (int off = 32; off >= 1; off >>= 1)
        g += __shfl_xor(g, off);
    int lastl = labels[(len - 1) * B_ + b];
    g += trans[STOP_I * K_ + lastl];

    if (lane == 0) out[b] = part - g;
}

extern "C" void kernel_launch(void* const* d_in, const int* in_sizes, int n_in,
                              void* d_out, int out_size, void* d_ws, size_t ws_size,
                              hipStream_t stream) {
    const float* emit = (const float*)d_in[0];
    const float* trans = (const float*)d_in[1];
    const int* labels = (const int*)d_in[2];
    const float* masks = (const float*)d_in[3];
    float* out = (float*)d_out;
    crf_kernel<<<B_, 64, 0, stream>>>(emit, trans, labels, masks, out);
}